// Round 4
// baseline (1072.420 us; speedup 1.0000x reference)
//
#include <hip/hip_runtime.h>
#include <hip/hip_bf16.h>

#define DIM   384
#define NWIN  49
#define HEADS 12
#define SCALE 0.17677669529663687f

typedef unsigned short ushort;
using bf16x8 = __attribute__((ext_vector_type(8))) short;
using u16x4  = __attribute__((ext_vector_type(4))) ushort;
using f32x4  = __attribute__((ext_vector_type(4))) float;

__device__ __forceinline__ ushort f2bf(float f) {
  unsigned u = __float_as_uint(f);
  u += 0x7fff + ((u >> 16) & 1);          // RNE
  return (ushort)(u >> 16);
}

typedef __attribute__((address_space(1))) const void gas_void;
typedef __attribute__((address_space(3))) void las_void;

__device__ __forceinline__ void gload16(const ushort* g, ushort* l) {
  __builtin_amdgcn_global_load_lds((gas_void*)g, (las_void*)l, 16, 0, 0);
}

// prep: bf16 weights (Wq prescaled), scaled qkv bias, bias+mask in MFMA-fragment layout
__global__ void prep_kernel(const float* __restrict__ qkv_w, const float* __restrict__ proj_w,
                            const float* __restrict__ bias_table, const int* __restrict__ rel_index,
                            const float* __restrict__ mask, const float* __restrict__ qkv_b,
                            ushort* __restrict__ wqb, ushort* __restrict__ wpb,
                            float* __restrict__ qbF, float* __restrict__ bmL) {
  int i0 = blockIdx.x * 256 + threadIdx.x;
  int stride = gridDim.x * 256;
  for (int i = i0; i < 1152 * 384; i += stride) {
    float v = qkv_w[i];
    if (i < 384 * 384) v *= SCALE;                 // fold softmax scale into Wq
    wqb[i] = f2bf(v);
  }
  for (int i = i0; i < 384 * 384; i += stride) wpb[i] = f2bf(proj_w[i]);
  for (int i = i0; i < 1152; i += stride) qbF[i] = qkv_b[i] * (i < 384 ? SCALE : 1.f);
  // bmL[wdx][h][wq][kt][r][lane] with masking baked in
  for (int i = i0; i < 64 * HEADS * 4 * 4 * 4 * 64; i += stride) {
    int l = i & 63, r = (i >> 6) & 3, kt = (i >> 8) & 3, wq = (i >> 10) & 3;
    int hw = i >> 12;
    int h = hw % 12, wdx = hw / 12;
    int q = wq * 16 + (l >> 4) * 4 + r;
    int key = kt * 16 + (l & 15);
    float v;
    if (q < NWIN)
      v = (key < NWIN) ? bias_table[rel_index[q * NWIN + key] * HEADS + h]
                         + mask[wdx * (NWIN * NWIN) + q * NWIN + key]
                       : -3.0e38f;
    else
      v = 0.f;
    bmL[i] = v;
  }
}

// LDS map (ushort units). Regions overlap only across dead phases:
//  WB  [0,36864)      : QKV chunks [96][192] x2 @ {0,18432}; proj [96][128] x2 @ {0,12288}
//  QS  [36864,41984)  : 2 win x [64][40]  (PS aliases QS)
//  KS  [41984,47104)  : 2 win x [64][40]
//  VT  [47104,51712)  : 2 win x [32][72]
//  X   [36864,75280)  : [98][392] initial x staging (dead after A-reg load)
//  AO  [24576,73728)  : [128][384] swizzled attn-out (written after last attention)
#define WB_OFF 0
#define QS_OFF 36864
#define KS_OFF 41984
#define VT_OFF 47104
#define X_OFF  36864
#define AO_OFF 24576
#define SMEM_US 75280   // 150560 bytes

__global__ __launch_bounds__(512) void winattn_kernel(
    const float* __restrict__ x, const float* __restrict__ qbF,
    const float* __restrict__ proj_b, const ushort* __restrict__ wqb,
    const ushort* __restrict__ wpb, const float* __restrict__ bmL,
    float* __restrict__ out)
{
  extern __shared__ ushort smem[];
  ushort* wb = smem + WB_OFF;
  ushort* xl = smem + X_OFF;
  ushort* ao = smem + AO_OFF;

  const int blk = blockIdx.x;
  const int tid = threadIdx.x;
  const int w = tid >> 6, l = tid & 63;
  const int c = l & 15, g = l >> 4;
  const int wm = w >> 1, wn = w & 1;      // GEMM wave grid: 4M x 2N
  const int win = w >> 2, wq = w & 3;     // attn wave grid: 2 windows x 4 q-tiles
  const float LOG2E = 1.4426950408889634f;

  ushort* qsw = smem + QS_OFF + win * 2560;
  ushort* ksw = smem + KS_OFF + win * 2560;
  ushort* vtw = smem + VT_OFF + win * 2304;
  ushort* psw = qsw;                      // PS aliases QS (per-wave row stripe)

  // ---- stage one QKV chunk [96 n][192 k] into wb half `buf` (src-side swizzle)
  auto stage_qkv = [&](int h, int kh, int buf) {
    #pragma unroll
    for (int s = 0; s < 5; ++s) {
      int i = s * 512 + tid;              // granule id, need < 2304
      if (i < 2304) {
        int n = i / 24, g16 = i - n * 24;
        int grow = (n >> 5) * 384 + h * 32 + (n & 31);
        int sg = (g16 & 24) | ((g16 & 7) ^ (n & 7));
        gload16(wqb + (size_t)grow * DIM + kh * 192 + (sg << 3),
                wb + buf * 18432 + i * 8);
      }
    }
  };
  // ---- stage one proj chunk [96 n][128 k]
  auto stage_proj = [&](int nb, int kh3, int buf) {
    #pragma unroll
    for (int s = 0; s < 3; ++s) {
      int i = s * 512 + tid;              // 1536 granules exactly
      int n = i >> 4, g16 = i & 15;
      int grow = nb * 96 + n;
      int sg = (g16 & 8) | ((g16 & 7) ^ (n & 7));
      gload16(wpb + (size_t)grow * DIM + kh3 * 128 + (sg << 3),
              wb + buf * 12288 + i * 8);
    }
  };

  // ---- QKV compute: A from registers, B from wb chunk
  bf16x8 areg[2][12] = {};
  auto compute_qkv = [&](int kh, int buf, f32x4 (&acc)[2][3]) {
    const ushort* wcb = wb + buf * 18432;
    #pragma unroll
    for (int kk = 0; kk < 6; ++kk) {
      int swz = ((kk * 4 + g) ^ (c & 7)) << 3;
      #pragma unroll
      for (int nt = 0; nt < 3; ++nt) {
        int n = (wn * 3 + nt) * 16 + c;
        bf16x8 bb = *(const bf16x8*)&wcb[n * 192 + swz];
        acc[0][nt] = __builtin_amdgcn_mfma_f32_16x16x32_bf16(areg[0][kh * 6 + kk], bb, acc[0][nt], 0, 0, 0);
        acc[1][nt] = __builtin_amdgcn_mfma_f32_16x16x32_bf16(areg[1][kh * 6 + kk], bb, acc[1][nt], 0, 0, 0);
      }
    }
  };
  // ---- proj compute: A from swizzled ao LDS, B from wb chunk
  auto compute_proj = [&](int kh3, int buf, f32x4 (&acc)[2][3]) {
    const ushort* wcb = wb + buf * 12288;
    #pragma unroll
    for (int kk = 0; kk < 4; ++kk) {
      int gcol = kh3 * 16 + kk * 4 + g;
      int sA = (gcol ^ (c & 7)) << 3;
      int row0 = wm * 32 + c;
      bf16x8 a0 = *(const bf16x8*)&ao[row0 * 384 + sA];
      bf16x8 a1 = *(const bf16x8*)&ao[(row0 + 16) * 384 + sA];
      int sB = ((kk * 4 + g) ^ (c & 7)) << 3;
      #pragma unroll
      for (int nt = 0; nt < 3; ++nt) {
        int n = (wn * 3 + nt) * 16 + c;
        bf16x8 bb = *(const bf16x8*)&wcb[n * 128 + sB];
        acc[0][nt] = __builtin_amdgcn_mfma_f32_16x16x32_bf16(a0, bb, acc[0][nt], 0, 0, 0);
        acc[1][nt] = __builtin_amdgcn_mfma_f32_16x16x32_bf16(a1, bb, acc[1][nt], 0, 0, 0);
      }
    }
  };

  // ---- prologue: prefetch head0 weights, stage x -> LDS, load A-regs
  stage_qkv(0, 0, 0);
  stage_qkv(0, 1, 1);
  {
    const float* xb = x + (size_t)blk * (2 * NWIN * DIM);
    for (int i = tid; i < 9408; i += 512) {        // float4 count = 2*49*384/4
      float4 f = ((const float4*)xb)[i];
      int widx = i / 4704;
      int rem = i - widx * 4704;
      int tok = rem / 96;
      int c4 = rem - tok * 96;
      u16x4 v4 = { f2bf(f.x), f2bf(f.y), f2bf(f.z), f2bf(f.w) };
      *(u16x4*)&xl[(widx * 49 + tok) * 392 + c4 * 4] = v4;
    }
  }
  __syncthreads();                                  // x visible (also drains prefetch)
  #pragma unroll
  for (int mt = 0; mt < 2; ++mt) {
    int row = wm * 32 + mt * 16 + c;
    int wi = row >> 6, tok = row & 63;
    if (tok < NWIN) {
      #pragma unroll
      for (int kkg = 0; kkg < 12; ++kkg)
        areg[mt][kkg] = *(const bf16x8*)&xl[(wi * 49 + tok) * 392 + kkg * 32 + g * 8];
    }
  }

  unsigned aop[48];   // packed bf16 attn-out stash [h][dt][rpair]

  // ================= per-head: QKV GEMM (A in regs) + attention =================
  #pragma unroll
  for (int h = 0; h < HEADS; ++h) {
    f32x4 acc[2][3] = {};
    #pragma unroll
    for (int kh = 0; kh < 2; ++kh) {
      compute_qkv(kh, kh, acc);
      __syncthreads();                   // all waves done with buf kh -> refill it
      if (h < 11) stage_qkv(h + 1, kh, kh);
      else        stage_proj(0, kh, kh);            // prefetch proj j=0,1
    }
    // epilogue: scatter q,k,v^T into per-window LDS buffers
    {
      int winE = wm >> 1;
      ushort* qsE = smem + QS_OFF + winE * 2560;
      ushort* ksE = smem + KS_OFF + winE * 2560;
      ushort* vtE = smem + VT_OFF + winE * 2304;
      #pragma unroll
      for (int nt = 0; nt < 3; ++nt) {
        int gnt = wn * 3 + nt;
        int which = gnt >> 1;
        int d = (gnt & 1) * 16 + c;
        float qb_ = qbF[which * 384 + h * 32 + d];
        #pragma unroll
        for (int mt = 0; mt < 2; ++mt) {
          #pragma unroll
          for (int r = 0; r < 4; ++r) {
            int tok = (wm & 1) * 32 + mt * 16 + g * 4 + r;
            float v = acc[mt][nt][r] + qb_;
            if (which == 0)      qsE[tok * 40 + d] = f2bf(v);
            else if (which == 1) ksE[tok * 40 + d] = f2bf(v);
            else                 vtE[d * 72 + tok] = f2bf(v);
          }
        }
      }
    }
    __syncthreads();

    // ---- attention for (win, q-tile wq)
    const int wdx = ((blk << 1) + win) & 63;
    const float* bw = bmL + ((size_t)((wdx * HEADS + h) * 4 + wq) << 10) + l;
    float bmv[4][4];
    #pragma unroll
    for (int kt = 0; kt < 4; ++kt)
      #pragma unroll
      for (int r = 0; r < 4; ++r)
        bmv[kt][r] = bw[(kt * 4 + r) << 6];

    f32x4 sacc[4] = {};
    {
      bf16x8 aq = *(const bf16x8*)&qsw[(wq * 16 + c) * 40 + g * 8];
      #pragma unroll
      for (int kt = 0; kt < 4; ++kt) {
        bf16x8 bk = *(const bf16x8*)&ksw[(kt * 16 + c) * 40 + g * 8];
        sacc[kt] = __builtin_amdgcn_mfma_f32_16x16x32_bf16(aq, bk, sacc[kt], 0, 0, 0);
      }
    }
    float p[4][4];
    #pragma unroll
    for (int r = 0; r < 4; ++r) {
      float s0 = sacc[0][r] + bmv[0][r], s1 = sacc[1][r] + bmv[1][r];
      float s2 = sacc[2][r] + bmv[2][r], s3 = sacc[3][r] + bmv[3][r];
      float mx = fmaxf(fmaxf(s0, s1), fmaxf(s2, s3));
      mx = fmaxf(mx, __shfl_xor(mx, 1, 64));
      mx = fmaxf(mx, __shfl_xor(mx, 2, 64));
      mx = fmaxf(mx, __shfl_xor(mx, 4, 64));
      mx = fmaxf(mx, __shfl_xor(mx, 8, 64));
      float p0 = __builtin_exp2f((s0 - mx) * LOG2E);
      float p1 = __builtin_exp2f((s1 - mx) * LOG2E);
      float p2 = __builtin_exp2f((s2 - mx) * LOG2E);
      float p3 = __builtin_exp2f((s3 - mx) * LOG2E);
      float sum = p0 + p1 + p2 + p3;
      sum += __shfl_xor(sum, 1, 64);
      sum += __shfl_xor(sum, 2, 64);
      sum += __shfl_xor(sum, 4, 64);
      sum += __shfl_xor(sum, 8, 64);
      float inv = 1.0f / sum;
      p[0][r] = p0 * inv; p[1][r] = p1 * inv; p[2][r] = p2 * inv; p[3][r] = p3 * inv;
    }
    // PV through wave-private ps stripe (aliases qs rows we own)
    f32x4 pacc2[2] = {};
    #pragma unroll
    for (int kkh = 0; kkh < 2; ++kkh) {
      #pragma unroll
      for (int t = 0; t < 2; ++t) {
        int kt = kkh * 2 + t;
        #pragma unroll
        for (int r = 0; r < 4; ++r)
          psw[(wq * 16 + g * 4 + r) * 40 + t * 16 + c] = f2bf(p[kt][r]);
      }
      bf16x8 ap = *(const bf16x8*)&psw[(wq * 16 + c) * 40 + g * 8];
      #pragma unroll
      for (int dt = 0; dt < 2; ++dt) {
        bf16x8 bv = *(const bf16x8*)&vtw[(dt * 16 + c) * 72 + kkh * 32 + g * 8];
        pacc2[dt] = __builtin_amdgcn_mfma_f32_16x16x32_bf16(ap, bv, pacc2[dt], 0, 0, 0);
      }
    }
    #pragma unroll
    for (int dt = 0; dt < 2; ++dt)
      #pragma unroll
      for (int rp = 0; rp < 2; ++rp)
        aop[h * 4 + dt * 2 + rp] = (unsigned)f2bf(pacc2[dt][2 * rp]) |
                                   ((unsigned)f2bf(pacc2[dt][2 * rp + 1]) << 16);
  }

  // ---- spill attn-out stash into swizzled ao LDS
  __syncthreads();                      // all attention reads of qs/ks/vt done
  #pragma unroll
  for (int h2 = 0; h2 < HEADS; ++h2) {
    #pragma unroll
    for (int dt = 0; dt < 2; ++dt) {
      #pragma unroll
      for (int rp = 0; rp < 2; ++rp) {
        unsigned u = aop[h2 * 4 + dt * 2 + rp];
        int gr = h2 * 4 + dt * 2 + (c >> 3);
        int row0 = win * 64 + wq * 16 + g * 4 + rp * 2;
        int row1 = row0 + 1;
        ao[row0 * 384 + (((gr ^ (row0 & 7)) << 3) | (c & 7))] = (ushort)(u & 0xffff);
        ao[row1 * 384 + (((gr ^ (row1 & 7)) << 3) | (c & 7))] = (ushort)(u >> 16);
      }
    }
  }
  __syncthreads();

  // ================= fused proj GEMM =================
  for (int nb = 0; nb < 4; ++nb) {
    f32x4 acc[2][3] = {};
    #pragma unroll
    for (int kh3 = 0; kh3 < 3; ++kh3) {
      int j = nb * 3 + kh3;
      compute_proj(kh3, j & 1, acc);
      __syncthreads();
      if (j + 2 < 12) {
        int nb2 = nb + (kh3 >= 1 ? 1 : 0);
        int kh2 = (kh3 + 2) % 3;
        stage_proj(nb2, kh2, j & 1);
      }
    }
    #pragma unroll
    for (int nt = 0; nt < 3; ++nt) {
      int col = nb * 96 + (wn * 3 + nt) * 16 + c;
      float pb = proj_b[col];
      #pragma unroll
      for (int mt = 0; mt < 2; ++mt) {
        #pragma unroll
        for (int r = 0; r < 4; ++r) {
          int mrow = wm * 32 + mt * 16 + g * 4 + r;
          int tok = mrow & 63;
          if (tok < NWIN)
            out[((size_t)((blk << 1) + (mrow >> 6)) * NWIN + tok) * DIM + col] =
                acc[mt][nt][r] + pb;
        }
      }
    }
  }
}

extern "C" void kernel_launch(void* const* d_in, const int* in_sizes, int n_in,
                              void* d_out, int out_size, void* d_ws, size_t ws_size,
                              hipStream_t stream) {
  const float* x          = (const float*)d_in[0];
  const float* mask       = (const float*)d_in[1];
  const float* bias_table = (const float*)d_in[2];
  const float* qkv_w      = (const float*)d_in[3];
  const float* qkv_b      = (const float*)d_in[4];
  const float* proj_w     = (const float*)d_in[5];
  const float* proj_b     = (const float*)d_in[6];
  const int*   rel_index  = (const int*)d_in[7];
  float* out = (float*)d_out;

  // ws: wqb @0 (884736 B) | wpb @884736 (294912) | qbF @1179648 (4608) | bmL @1184256 (12582912)
  ushort* wqb = (ushort*)d_ws;
  ushort* wpb = (ushort*)((char*)d_ws + 884736);
  float*  qbF = (float*)((char*)d_ws + 1179648);
  float*  bmL = (float*)((char*)d_ws + 1184256);

  hipFuncSetAttribute((const void*)winattn_kernel,
                      hipFuncAttributeMaxDynamicSharedMemorySize, SMEM_US * 2);

  prep_kernel<<<1024, 256, 0, stream>>>(qkv_w, proj_w, bias_table, rel_index, mask, qkv_b,
                                        wqb, wpb, qbF, bmL);
  winattn_kernel<<<2048, 512, SMEM_US * 2, stream>>>(
      x, qbF, proj_b, wqb, wpb, bmL, out);
}

// Round 5
// 816.597 us; speedup vs baseline: 1.3133x; 1.3133x over previous
//
#include <hip/hip_runtime.h>
#include <hip/hip_bf16.h>

#define DIM   384
#define NWIN  49
#define HEADS 12
#define SCALE 0.17677669529663687f

typedef unsigned short ushort;
using bf16x8 = __attribute__((ext_vector_type(8))) short;
using u16x4  = __attribute__((ext_vector_type(4))) ushort;
using f32x4  = __attribute__((ext_vector_type(4))) float;

__device__ __forceinline__ ushort f2bf(float f) {
  unsigned u = __float_as_uint(f);
  u += 0x7fff + ((u >> 16) & 1);          // RNE
  return (ushort)(u >> 16);
}

typedef __attribute__((address_space(1))) const void gas_void;
typedef __attribute__((address_space(3))) void las_void;

__device__ __forceinline__ void gload16(const ushort* g, ushort* l) {
  __builtin_amdgcn_global_load_lds((gas_void*)g, (las_void*)l, 16, 0, 0);
}

// prep: bf16 weights (Wq prescaled), scaled qkv bias, bias+mask in MFMA-fragment layout
__global__ void prep_kernel(const float* __restrict__ qkv_w, const float* __restrict__ proj_w,
                            const float* __restrict__ bias_table, const int* __restrict__ rel_index,
                            const float* __restrict__ mask, const float* __restrict__ qkv_b,
                            ushort* __restrict__ wqb, ushort* __restrict__ wpb,
                            float* __restrict__ qbF, float* __restrict__ bmL) {
  int i0 = blockIdx.x * 256 + threadIdx.x;
  int stride = gridDim.x * 256;
  for (int i = i0; i < 1152 * 384; i += stride) {
    float v = qkv_w[i];
    if (i < 384 * 384) v *= SCALE;                 // fold softmax scale into Wq
    wqb[i] = f2bf(v);
  }
  for (int i = i0; i < 384 * 384; i += stride) wpb[i] = f2bf(proj_w[i]);
  for (int i = i0; i < 1152; i += stride) qbF[i] = qkv_b[i] * (i < 384 ? SCALE : 1.f);
  // bmL[wdx][h][wq][kt][r][lane] with masking baked in
  for (int i = i0; i < 64 * HEADS * 4 * 4 * 4 * 64; i += stride) {
    int l = i & 63, r = (i >> 6) & 3, kt = (i >> 8) & 3, wq = (i >> 10) & 3;
    int hw = i >> 12;
    int h = hw % 12, wdx = hw / 12;
    int q = wq * 16 + (l >> 4) * 4 + r;
    int key = kt * 16 + (l & 15);
    float v;
    if (q < NWIN)
      v = (key < NWIN) ? bias_table[rel_index[q * NWIN + key] * HEADS + h]
                         + mask[wdx * (NWIN * NWIN) + q * NWIN + key]
                       : -3.0e38f;
    else
      v = 0.f;
    bmL[i] = v;
  }
}

// LDS map (ushort units), all regions DISJOINT (ao live across whole kernel):
//  WB [0,24576)      : 2 x [96][128] weight chunks (qkv & proj share shape)
//  QS [24576,29696)  : 2 win x [64][40]   (PS aliases QS, per-wave row stripes)
//  KS [29696,34816)  : 2 win x [64][40]
//  VT [34816,39424)  : 2 win x [32][72]
//  AO [39424,77056)  : [98][384] swizzled: x at start, attn-out per head
#define WB_OFF 0
#define QS_OFF 24576
#define KS_OFF 29696
#define VT_OFF 34816
#define AO_OFF 39424
#define SMEM_US 77056   // 154112 bytes

__global__ __launch_bounds__(512, 2) void winattn_kernel(
    const float* __restrict__ x, const float* __restrict__ qbF,
    const float* __restrict__ proj_b, const ushort* __restrict__ wqb,
    const ushort* __restrict__ wpb, const float* __restrict__ bmL,
    float* __restrict__ out)
{
  extern __shared__ ushort smem[];
  ushort* wb = smem + WB_OFF;
  ushort* ao = smem + AO_OFF;

  const int blk = blockIdx.x;
  const int tid = threadIdx.x;
  const int w = tid >> 6, l = tid & 63;
  const int c = l & 15, g = l >> 4;
  const int wm = w >> 1, wn = w & 1;      // GEMM wave grid: 4M x 2N
  const int win = w >> 2, wq = w & 3;     // attn wave grid: 2 windows x 4 q-tiles
  const float LOG2E = 1.4426950408889634f;

  ushort* qsw = smem + QS_OFF + win * 2560;
  ushort* ksw = smem + KS_OFF + win * 2560;
  ushort* vtw = smem + VT_OFF + win * 2304;
  ushort* psw = qsw;                      // PS aliases QS (per-wave row stripe)

  // stage one [96 n][128 k] qkv chunk (rows q32|k32|v32 of head h) into wb half `buf`
  auto stage_qkv = [&](int h, int kc, int buf) {
    #pragma unroll
    for (int s = 0; s < 3; ++s) {
      int i = s * 512 + tid;              // 1536 granules exactly
      int n = i >> 4, g16 = i & 15;
      int grow = (n >> 5) * 384 + h * 32 + (n & 31);
      int sg = (g16 & 8) | ((g16 & 7) ^ (n & 7));
      gload16(wqb + (size_t)grow * DIM + kc * 128 + (sg << 3),
              wb + buf * 12288 + i * 8);
    }
  };
  // stage one [96 n][128 k] proj chunk
  auto stage_proj = [&](int nb, int kc, int buf) {
    #pragma unroll
    for (int s = 0; s < 3; ++s) {
      int i = s * 512 + tid;
      int n = i >> 4, g16 = i & 15;
      int grow = nb * 96 + n;
      int sg = (g16 & 8) | ((g16 & 7) ^ (n & 7));
      gload16(wpb + (size_t)grow * DIM + kc * 128 + (sg << 3),
              wb + buf * 12288 + i * 8);
    }
  };

  // ---- QKV compute: A from registers (static idx: kc/kk unrolled), B from wb
  bf16x8 areg[2][12] = {};
  auto compute_qkv = [&](int kcC, int buf, f32x4 (&acc)[2][3]) {
    const ushort* wcb = wb + buf * 12288;
    #pragma unroll
    for (int kk = 0; kk < 4; ++kk) {
      int sB = ((kk * 4 + g) ^ (c & 7)) << 3;
      #pragma unroll
      for (int nt = 0; nt < 3; ++nt) {
        int n = (wn * 3 + nt) * 16 + c;
        bf16x8 bb = *(const bf16x8*)&wcb[n * 128 + sB];
        acc[0][nt] = __builtin_amdgcn_mfma_f32_16x16x32_bf16(areg[0][kcC * 4 + kk], bb, acc[0][nt], 0, 0, 0);
        acc[1][nt] = __builtin_amdgcn_mfma_f32_16x16x32_bf16(areg[1][kcC * 4 + kk], bb, acc[1][nt], 0, 0, 0);
      }
    }
  };
  // ---- proj compute: A from swizzled ao LDS (98 valid rows, clamp padding reads)
  auto compute_proj = [&](int kcC, int buf, f32x4 (&acc)[2][3]) {
    const ushort* wcb = wb + buf * 12288;
    int r0 = wm * 32 + c;      if (r0 >= 98) r0 -= 64;   // valid-garbage row
    int r1 = wm * 32 + 16 + c; if (r1 >= 98) r1 -= 64;
    #pragma unroll
    for (int kk = 0; kk < 4; ++kk) {
      int p = kcC * 16 + kk * 4 + g;
      int sw = (p ^ (c & 7)) << 3;        // r0&7 == r1&7 == c&7 (clamp is -64)
      bf16x8 a0 = *(const bf16x8*)&ao[r0 * 384 + sw];
      bf16x8 a1 = *(const bf16x8*)&ao[r1 * 384 + sw];
      int sB = ((kk * 4 + g) ^ (c & 7)) << 3;
      #pragma unroll
      for (int nt = 0; nt < 3; ++nt) {
        int n = (wn * 3 + nt) * 16 + c;
        bf16x8 bb = *(const bf16x8*)&wcb[n * 128 + sB];
        acc[0][nt] = __builtin_amdgcn_mfma_f32_16x16x32_bf16(a0, bb, acc[0][nt], 0, 0, 0);
        acc[1][nt] = __builtin_amdgcn_mfma_f32_16x16x32_bf16(a1, bb, acc[1][nt], 0, 0, 0);
      }
    }
  };

  // ---- prologue: prefetch first two chunks; stage x (2 windows) swizzled into AO
  stage_qkv(0, 0, 0);
  stage_qkv(0, 1, 1);
  {
    const float* xb = x + (size_t)blk * (2 * NWIN * DIM);
    for (int i = tid; i < 9408; i += 512) {        // 9408 float4 = 98 rows x 96
      float4 f = ((const float4*)xb)[i];
      int row = i / 96;                            // 0..97 (= win*49+tok)
      int c4 = i - row * 96;
      int k = c4 * 4;
      int gr = k >> 3;
      u16x4 v4 = { f2bf(f.x), f2bf(f.y), f2bf(f.z), f2bf(f.w) };
      *(u16x4*)&ao[row * 384 + ((gr ^ (row & 7)) << 3) + (k & 7)] = v4;
    }
  }
  __syncthreads();                                  // x visible; prefetch drained

  // A fragments: logical M = 128 (2 win x 64 padded); rows >=49/window are zero
  #pragma unroll
  for (int mt = 0; mt < 2; ++mt) {
    int row = wm * 32 + mt * 16 + c;
    int wi = row >> 6, tok = row & 63;
    if (tok < NWIN) {
      int ar = wi * 49 + tok;
      #pragma unroll
      for (int kg = 0; kg < 12; ++kg) {
        int gx = kg * 4 + g;
        areg[mt][kg] = *(const bf16x8*)&ao[ar * 384 + ((gx ^ (ar & 7)) << 3)];
      }
    }
  }

  // ================= per-head: QKV GEMM (A in regs) + attention =================
  for (int h = 0; h < HEADS; ++h) {
    f32x4 acc[2][3] = {};
    const int par = h & 1;                // buf of kc0 = (3h)&1

    compute_qkv(0, par, acc);
    __syncthreads();
    stage_qkv(h, 2, par);

    compute_qkv(1, par ^ 1, acc);
    __syncthreads();
    if (h < 11) stage_qkv(h + 1, 0, par ^ 1); else stage_proj(0, 0, par ^ 1);

    compute_qkv(2, par, acc);
    __syncthreads();
    if (h < 11) stage_qkv(h + 1, 1, par); else stage_proj(0, 1, par);

    // epilogue: scatter q,k,v^T into per-window LDS buffers
    {
      int winE = wm >> 1;
      ushort* qsE = smem + QS_OFF + winE * 2560;
      ushort* ksE = smem + KS_OFF + winE * 2560;
      ushort* vtE = smem + VT_OFF + winE * 2304;
      #pragma unroll
      for (int nt = 0; nt < 3; ++nt) {
        int gnt = wn * 3 + nt;
        int which = gnt >> 1;
        int d = (gnt & 1) * 16 + c;
        float qb_ = qbF[which * 384 + h * 32 + d];
        #pragma unroll
        for (int mt = 0; mt < 2; ++mt) {
          #pragma unroll
          for (int r = 0; r < 4; ++r) {
            int tok = (wm & 1) * 32 + mt * 16 + g * 4 + r;
            float v = acc[mt][nt][r] + qb_;
            if (which == 0)      qsE[tok * 40 + d] = f2bf(v);
            else if (which == 1) ksE[tok * 40 + d] = f2bf(v);
            else                 vtE[d * 72 + tok] = f2bf(v);
          }
        }
      }
    }
    __syncthreads();

    // ---- attention for (win, q-tile wq)
    const int wdx = ((blk << 1) + win) & 63;
    const float* bw = bmL + ((size_t)((wdx * HEADS + h) * 4 + wq) << 10) + l;
    float bmv[4][4];
    #pragma unroll
    for (int kt = 0; kt < 4; ++kt)
      #pragma unroll
      for (int r = 0; r < 4; ++r)
        bmv[kt][r] = bw[(kt * 4 + r) << 6];

    f32x4 sacc[4] = {};
    {
      bf16x8 aq = *(const bf16x8*)&qsw[(wq * 16 + c) * 40 + g * 8];
      #pragma unroll
      for (int kt = 0; kt < 4; ++kt) {
        bf16x8 bk = *(const bf16x8*)&ksw[(kt * 16 + c) * 40 + g * 8];
        sacc[kt] = __builtin_amdgcn_mfma_f32_16x16x32_bf16(aq, bk, sacc[kt], 0, 0, 0);
      }
    }
    float p[4][4];
    #pragma unroll
    for (int r = 0; r < 4; ++r) {
      float s0 = sacc[0][r] + bmv[0][r], s1 = sacc[1][r] + bmv[1][r];
      float s2 = sacc[2][r] + bmv[2][r], s3 = sacc[3][r] + bmv[3][r];
      float mx = fmaxf(fmaxf(s0, s1), fmaxf(s2, s3));
      mx = fmaxf(mx, __shfl_xor(mx, 1, 64));
      mx = fmaxf(mx, __shfl_xor(mx, 2, 64));
      mx = fmaxf(mx, __shfl_xor(mx, 4, 64));
      mx = fmaxf(mx, __shfl_xor(mx, 8, 64));
      float p0 = __builtin_exp2f((s0 - mx) * LOG2E);
      float p1 = __builtin_exp2f((s1 - mx) * LOG2E);
      float p2 = __builtin_exp2f((s2 - mx) * LOG2E);
      float p3 = __builtin_exp2f((s3 - mx) * LOG2E);
      float sum = p0 + p1 + p2 + p3;
      sum += __shfl_xor(sum, 1, 64);
      sum += __shfl_xor(sum, 2, 64);
      sum += __shfl_xor(sum, 4, 64);
      sum += __shfl_xor(sum, 8, 64);
      float inv = 1.0f / sum;
      p[0][r] = p0 * inv; p[1][r] = p1 * inv; p[2][r] = p2 * inv; p[3][r] = p3 * inv;
    }
    // PV through wave-private ps stripe (aliases qs rows we own)
    f32x4 pacc2[2] = {};
    #pragma unroll
    for (int kkh = 0; kkh < 2; ++kkh) {
      #pragma unroll
      for (int t = 0; t < 2; ++t) {
        int kt = kkh * 2 + t;
        #pragma unroll
        for (int r = 0; r < 4; ++r)
          psw[(wq * 16 + g * 4 + r) * 40 + t * 16 + c] = f2bf(p[kt][r]);
      }
      bf16x8 ap = *(const bf16x8*)&psw[(wq * 16 + c) * 40 + g * 8];
      #pragma unroll
      for (int dt = 0; dt < 2; ++dt) {
        bf16x8 bv = *(const bf16x8*)&vtw[(dt * 16 + c) * 72 + kkh * 32 + g * 8];
        pacc2[dt] = __builtin_amdgcn_mfma_f32_16x16x32_bf16(ap, bv, pacc2[dt], 0, 0, 0);
      }
    }
    // write attn-out DIRECTLY into swizzled ao LDS (no register stash)
    #pragma unroll
    for (int dt = 0; dt < 2; ++dt) {
      int gr0 = h * 4 + dt * 2 + (c >> 3);         // granule of col h*32+dt*16+c
      #pragma unroll
      for (int rp = 0; rp < 2; ++rp) {
        int tok0 = wq * 16 + g * 4 + rp * 2;
        int row0 = win * 49 + tok0;
        if (tok0 < NWIN)
          ao[row0 * 384 + (((gr0 ^ (row0 & 7)) << 3) | (c & 7))] = f2bf(pacc2[dt][2 * rp]);
        if (tok0 + 1 < NWIN)
          ao[(row0 + 1) * 384 + (((gr0 ^ ((row0 + 1) & 7)) << 3) | (c & 7))] = f2bf(pacc2[dt][2 * rp + 1]);
      }
    }
  }

  __syncthreads();                       // all ao writes visible

  // ================= fused proj GEMM (M = 98 compact rows) =================
  for (int nb = 0; nb < 4; ++nb) {
    f32x4 acc[2][3] = {};
    const int pb0 = (nb * 3) & 1;

    compute_proj(0, pb0, acc);
    __syncthreads();
    stage_proj(nb, 2, pb0);

    compute_proj(1, pb0 ^ 1, acc);
    __syncthreads();
    if (nb < 3) stage_proj(nb + 1, 0, pb0 ^ 1);

    compute_proj(2, pb0, acc);
    __syncthreads();
    if (nb < 3) stage_proj(nb + 1, 1, pb0);

    #pragma unroll
    for (int nt = 0; nt < 3; ++nt) {
      int col = nb * 96 + (wn * 3 + nt) * 16 + c;
      float pb = proj_b[col];
      #pragma unroll
      for (int mt = 0; mt < 2; ++mt) {
        #pragma unroll
        for (int r = 0; r < 4; ++r) {
          int mrow = wm * 32 + mt * 16 + g * 4 + r;
          if (mrow < 98) {
            int wi = mrow >= NWIN;
            int tok = mrow - (wi ? NWIN : 0);
            out[((size_t)((blk << 1) + wi) * NWIN + tok) * DIM + col] =
                acc[mt][nt][r] + pb;
          }
        }
      }
    }
  }
}

extern "C" void kernel_launch(void* const* d_in, const int* in_sizes, int n_in,
                              void* d_out, int out_size, void* d_ws, size_t ws_size,
                              hipStream_t stream) {
  const float* x          = (const float*)d_in[0];
  const float* mask       = (const float*)d_in[1];
  const float* bias_table = (const float*)d_in[2];
  const float* qkv_w      = (const float*)d_in[3];
  const float* qkv_b      = (const float*)d_in[4];
  const float* proj_w     = (const float*)d_in[5];
  const float* proj_b     = (const float*)d_in[6];
  const int*   rel_index  = (const int*)d_in[7];
  float* out = (float*)d_out;

  // ws: wqb @0 (884736 B) | wpb @884736 (294912) | qbF @1179648 (4608) | bmL @1184256 (12582912)
  ushort* wqb = (ushort*)d_ws;
  ushort* wpb = (ushort*)((char*)d_ws + 884736);
  float*  qbF = (float*)((char*)d_ws + 1179648);
  float*  bmL = (float*)((char*)d_ws + 1184256);

  hipFuncSetAttribute((const void*)winattn_kernel,
                      hipFuncAttributeMaxDynamicSharedMemorySize, SMEM_US * 2);

  prep_kernel<<<1024, 256, 0, stream>>>(qkv_w, proj_w, bias_table, rel_index, mask, qkv_b,
                                        wqb, wpb, qbF, bmL);
  winattn_kernel<<<2048, 512, SMEM_US * 2, stream>>>(
      x, qbF, proj_b, wqb, wpb, bmL, out);
}